// Round 5
// baseline (192.014 us; speedup 1.0000x reference)
//
#include <hip/hip_runtime.h>
#include <hip/hip_bf16.h>
#include <stdint.h>

// Problem constants
#define B_SZ   1024
#define GF     512     // gating features
#define GC     63      // gate count
#define NLEAF  64
#define IN_F   512
#define OUT_F  512

typedef float f32x4 __attribute__((ext_vector_type(4)));
typedef __bf16 bf16x8 __attribute__((ext_vector_type(8)));

struct alignas(16) BV8 { __hip_bfloat162 a, b, c, d; };  // 8 bf16 = 16B
union PK8 { BV8 v; bf16x8 f; };
union BU { __hip_bfloat162 h; unsigned int u; };

// s_waitcnt imm (gfx9 encoding): vmcnt[3:0]=b0-3, expcnt=b4-6, lgkmcnt=b8-11,
// vmcnt[5:4]=b14-15. vmcnt(16), exp/lgkm no-wait: high=01 -> 0x4000|0xF00|0x70.
#define WAIT_VM16 0x4F70

// ---------------------------------------------------------------------------
// Kernel 1 (fused): blocks [0,1024) -> leaf_probs; blocks [1024,9216) ->
// pw fp32 [o][i][l] -> pwb bf16 [i][o][l] conversion.
// ---------------------------------------------------------------------------
__global__ __launch_bounds__(512, 2) void k_prep(
    const float* __restrict__ xg, const float* __restrict__ gw,
    const float* __restrict__ gb, float* __restrict__ p_ws,
    const float* __restrict__ pw, __hip_bfloat16* __restrict__ pwb)
{
  __shared__ float xsr[GF];
  __shared__ float part[512];
  __shared__ float gates[GC + 1];
  const int blk = blockIdx.x;
  const int t   = threadIdx.x;

  if (blk < B_SZ) {
    const int b = blk;
    xsr[t] = xg[(size_t)b * GF + t];
    __syncthreads();

    const int ks = t >> 6;
    const int g  = t & 63;
    float acc = 0.f;
    if (g < GC) {
      const float* gp = gw + (size_t)(ks * 64) * GC + g;
      const float* xp = &xsr[ks * 64];
#pragma unroll 8
      for (int k = 0; k < 64; ++k) acc += xp[k] * gp[(size_t)k * GC];
    }
    part[t] = acc;
    __syncthreads();

    if (t < GC) {
      float s = gb[t];
#pragma unroll
      for (int r = 0; r < 8; ++r) s += part[r * 64 + t];
      gates[t] = 1.f / (1.f + expf(-s));
    }
    __syncthreads();

    if (t < NLEAF) {
      float v = 1.f;
      int idx = 0, start = 0;
#pragma unroll
      for (int d = 0; d < 6; ++d) {
        int bit = (t >> (5 - d)) & 1;
        float gg = gates[start + idx];
        v *= bit ? (1.f - gg) : gg;
        idx = 2 * idx + bit;
        start += (1 << d);
      }
      p_ws[(size_t)b * NLEAF + t] = v;
    }
  } else {
    const int tt = (blk - B_SZ) * 512 + t;
    const int l4 = (tt & 15) * 4;
    const int o  = (tt >> 4) & 511;
    const int i  = tt >> 13;

    float4 v = *(const float4*)(pw + ((size_t)o * IN_F + i) * NLEAF + l4);
    BU ua, ub;
    ua.h = __float22bfloat162_rn(make_float2(v.x, v.y));
    ub.h = __float22bfloat162_rn(make_float2(v.z, v.w));
    uint2 outv = make_uint2(ua.u, ub.u);
    *(uint2*)(pwb + (size_t)i * (OUT_F * NLEAF) + (size_t)o * NLEAF + l4) = outv;
  }
}

// ---------------------------------------------------------------------------
// Kernel 2: main GEMM with BARRIER-FREE K-loop (wave-private B staging).
// out[b][o] (+)= sum_{i,l} (x[b][i]*p[b][l]) * pwb[i][o][l]
// Block = 2 waves, BM=64, BN=128; wave = 64m x 64n PRIVATE n-tile -> no
// cross-wave B sharing -> no __syncthreads in the loop. Per-wave 4-buffer
// glds pipeline, 3 tiles (24 glds) in flight, gated by s_waitcnt vmcnt(16).
// Tail: dup-issue of the last tile keeps the count uniform (targets a buffer
// whose tenant is already consumed; mod-4 rotation makes it non-conflicting).
// A built in registers (p fp32 in VGPRs, x via LDS broadcast), single round.
// ---------------------------------------------------------------------------
template <int SK, bool ATOMIC>
__global__ __launch_bounds__(128, 1) void k_gemm(
    const float* __restrict__ x_leaf,          // [1024][512]
    const float* __restrict__ p_ws,            // [1024][64]
    const __hip_bfloat16* __restrict__ pwb,    // [512][512][64]  ([i][o][l])
    float* __restrict__ dst)                   // parts [SK][1024][512] or out
{
  constexpr int KI = 512 / SK;
  __shared__ __align__(16) float           xs[64][KI + 4];
  __shared__ __align__(16) __hip_bfloat16  bs[2][4][4096];  // [wave][buf] 64 KB

  const int tid  = threadIdx.x;
  const int lane = tid & 63;
  const int wid  = tid >> 6;        // 0..1
  const int quad = lane >> 4;
  const int l15  = lane & 15;

  // XCD swizzle: xcd fixes (nt, kc-parity) -> per-XCD pwb footprint = 4 MB (L2)
  const int bid = blockIdx.x;       // SK*64 blocks
  const int xcd = bid & 7;
  const int j   = bid >> 3;
  const int nt  = xcd & 3;
  const int kcl = xcd >> 2;
  const int mt  = j & 15;
  const int kch = j >> 4;
  const int kc  = kch * 2 + kcl;    // 0..SK-1

  const int row_m0 = mt * 64;
  const int col_n0 = nt * 128;
  const int i0     = kc * KI;
  const int wn     = wid * 64;      // wave-private n-half

  // ---- stage x slab [64 rows][KI] (both waves read all rows) ----
  {
    int r = tid >> 1, h = tid & 1;
    const float* src = x_leaf + (size_t)(row_m0 + r) * IN_F + i0 + h * (KI / 2);
#pragma unroll
    for (int q = 0; q < KI / 8; ++q)
      *(float4*)&xs[r][h * (KI / 2) + q * 4] = *(const float4*)(src + q * 4);
  }

  // ---- p fragments fp32 (reused all K): pr[mi][ks][half4] ----
  f32x4 pr[4][2][2];
#pragma unroll
  for (int mi = 0; mi < 4; ++mi) {
    int row = row_m0 + mi * 16 + l15;
#pragma unroll
    for (int ks = 0; ks < 2; ++ks) {
      const f32x4* src = (const f32x4*)(p_ws + (size_t)row * NLEAF + ks * 32 + quad * 8);
      pr[mi][ks][0] = src[0];
      pr[mi][ks][1] = src[1];
    }
  }
  // Force p into registers BEFORE the loop so the compiler's vmem-wait for p
  // lands here, not inside the K-loop (where it would over-wait our glds).
  {
    float sink = 0.f;
#pragma unroll
    for (int mi = 0; mi < 4; ++mi)
#pragma unroll
      for (int ks = 0; ks < 2; ++ks)
#pragma unroll
        for (int h = 0; h < 2; ++h) {
          f32x4 v = pr[mi][ks][h];
          sink += v.x + v.y + v.z + v.w;
        }
    if (sink == 1.2345678e37f) xs[0][0] = sink;   // never taken
  }

  // ---- per-lane glds source offsets (XOR-rotated rows), wave-private tile ----
  int boff[8];
#pragma unroll
  for (int v = 0; v < 8; ++v) {
    int n = v * 8 + (lane >> 3);            // 0..63 local row
    int c = lane & 7;
    int q = (c - n) & 7;
    boff[v] = (col_n0 + wn + n) * NLEAF + q * 8;
  }

  f32x4 acc[4][4];
#pragma unroll
  for (int mi = 0; mi < 4; ++mi)
#pragma unroll
    for (int ni = 0; ni < 4; ++ni)
      acc[mi][ni] = (f32x4)(0.f);

  __syncthreads();   // xs ready; glds not yet issued -> pipeline unharmed

#define ISSUE(T, S)                                                           \
  {                                                                           \
    const __hip_bfloat16* gi_ = pwb + ((size_t)(i0 + (T)) << 15);             \
    __hip_bfloat16* db_ = &bs[wid][S][0];                                     \
    _Pragma("unroll")                                                         \
    for (int v_ = 0; v_ < 8; ++v_)                                            \
      __builtin_amdgcn_global_load_lds(                                       \
          (const __attribute__((address_space(1))) void*)(gi_ + boff[v_]),    \
          (__attribute__((address_space(3))) void*)(db_ + v_ * 512),          \
          16, 0, 0);                                                          \
  }

  // prologue: 3 tiles in flight (24 glds)
  ISSUE(0, 0)
  ISSUE(1, 1)
  ISSUE(2, 2)

#pragma unroll 4
  for (int ii = 0; ii < KI; ++ii) {
    // gate: oldest tile (ii) arrived when <=16 glds outstanding
    __builtin_amdgcn_s_waitcnt(WAIT_VM16);
    __builtin_amdgcn_sched_barrier(0);   // pin ds_reads behind the wait

    // keep 8 issues/iter (uniform count); tail dup-issues tile KI-1 into a
    // buffer whose tenant is already consumed
    int tnext = (ii + 3 < KI) ? (ii + 3) : (KI - 1);
    ISSUE(tnext, (ii + 3) & 3)

    const __hip_bfloat16* bsc = &bs[wid][ii & 3][0];
    float xv[4];
#pragma unroll
    for (int mi = 0; mi < 4; ++mi) xv[mi] = xs[mi * 16 + l15][ii];

#pragma unroll
    for (int ks = 0; ks < 2; ++ks) {
      bf16x8 af[4];
#pragma unroll
      for (int mi = 0; mi < 4; ++mi) {
        f32x4 lo = pr[mi][ks][0] * xv[mi];
        f32x4 hi = pr[mi][ks][1] * xv[mi];
        PK8 u;
        u.v.a = __float22bfloat162_rn(make_float2(lo.x, lo.y));
        u.v.b = __float22bfloat162_rn(make_float2(lo.z, lo.w));
        u.v.c = __float22bfloat162_rn(make_float2(hi.x, hi.y));
        u.v.d = __float22bfloat162_rn(make_float2(hi.z, hi.w));
        af[mi] = u.f;
      }
#pragma unroll
      for (int ni = 0; ni < 4; ++ni) {
        int n = ni * 16 + l15;
        bf16x8 bfr = *(const bf16x8*)&bsc[n * 64 + (((ks * 4 + quad + n) & 7) << 3)];
#pragma unroll
        for (int mi = 0; mi < 4; ++mi)
          acc[mi][ni] = __builtin_amdgcn_mfma_f32_16x16x32_bf16(
              af[mi], bfr, acc[mi][ni], 0, 0, 0);
      }
    }
  }
#undef ISSUE

  // ---- epilogue ----
#pragma unroll
  for (int mi = 0; mi < 4; ++mi) {
#pragma unroll
    for (int ni = 0; ni < 4; ++ni) {
      int row = row_m0 + mi * 16 + quad * 4;
      int col = col_n0 + wn + ni * 16 + l15;
      if (ATOMIC) {
        float* o0 = dst + (size_t)row * OUT_F + col;
        atomicAdd(o0,             acc[mi][ni][0]);
        atomicAdd(o0 + OUT_F,     acc[mi][ni][1]);
        atomicAdd(o0 + 2 * OUT_F, acc[mi][ni][2]);
        atomicAdd(o0 + 3 * OUT_F, acc[mi][ni][3]);
      } else {
        float* o0 = dst + ((size_t)kc << 19) + (size_t)row * OUT_F + col;
        o0[0]         = acc[mi][ni][0];
        o0[OUT_F]     = acc[mi][ni][1];
        o0[2 * OUT_F] = acc[mi][ni][2];
        o0[3 * OUT_F] = acc[mi][ni][3];
      }
    }
  }
}

// ---------------------------------------------------------------------------
// Kernel 3: out[b][o] = sum_kc parts[kc][b][o] + sum_l p[b][l]*pb[o][l]
// nparts==0: bias-only init (atomic-fallback path).
// ---------------------------------------------------------------------------
__global__ __launch_bounds__(256, 4) void k_reduce(
    const float* __restrict__ parts, const float* __restrict__ p_ws,
    const float* __restrict__ pb, float* __restrict__ out, int nparts)
{
  __shared__ float ps_l[2 * NLEAF];
  const int t  = threadIdx.x;
  const int b0 = blockIdx.x * 2;

  if (t < 32)
    ((f32x4*)ps_l)[t] = ((const f32x4*)(p_ws + (size_t)b0 * NLEAF))[t];
  __syncthreads();

  const int row = b0 + (t >> 7);
  const int c0  = (t & 127) * 4;
  const f32x4* ps = (const f32x4*)&ps_l[(t >> 7) * NLEAF];

  f32x4 a;
#pragma unroll
  for (int jo = 0; jo < 4; ++jo) {
    const f32x4* pbo = (const f32x4*)(pb + (size_t)(c0 + jo) * NLEAF);
    f32x4 s = (f32x4)(0.f);
#pragma unroll
    for (int lv = 0; lv < 16; ++lv) s += pbo[lv] * ps[lv];
    a[jo] = s.x + s.y + s.z + s.w;
  }

#pragma unroll 8
  for (int k = 0; k < nparts; ++k)
    a += *(const f32x4*)(parts + ((size_t)k << 19) + (size_t)row * OUT_F + c0);

  *(f32x4*)(out + (size_t)row * OUT_F + c0) = a;
}

// ---------------------------------------------------------------------------
extern "C" void kernel_launch(void* const* d_in, const int* in_sizes, int n_in,
                              void* d_out, int out_size, void* d_ws, size_t ws_size,
                              hipStream_t stream) {
  const float* xg = (const float*)d_in[0];
  const float* xl = (const float*)d_in[1];
  const float* gw = (const float*)d_in[2];
  const float* gb = (const float*)d_in[3];
  const float* pw = (const float*)d_in[4];
  const float* pb = (const float*)d_in[5];
  float* out = (float*)d_out;

  // ws layout: pwb bf16 (33.55 MB) | p fp32 (256 KB) | parts fp32 (SK x 2 MB)
  const size_t PWB_BYTES = (size_t)IN_F * OUT_F * NLEAF * 2;
  const size_t P_BYTES   = (size_t)B_SZ * NLEAF * 4;
  const size_t SLICE     = (size_t)B_SZ * OUT_F * 4;

  __hip_bfloat16* pwb = (__hip_bfloat16*)d_ws;
  float* p_ws  = (float*)((char*)d_ws + PWB_BYTES);
  float* parts = (float*)((char*)d_ws + PWB_BYTES + P_BYTES);
  const size_t base = PWB_BYTES + P_BYTES;

  k_prep<<<dim3(B_SZ + 8192), dim3(512), 0, stream>>>(xg, gw, gb, p_ws, pw, pwb);

  if (ws_size >= base + 16 * SLICE) {
    k_gemm<16, false><<<dim3(1024), dim3(128), 0, stream>>>(xl, p_ws, pwb, parts);
    k_reduce<<<dim3(512), dim3(256), 0, stream>>>(parts, p_ws, pb, out, 16);
  } else if (ws_size >= base + 8 * SLICE) {
    k_gemm<8, false><<<dim3(512), dim3(128), 0, stream>>>(xl, p_ws, pwb, parts);
    k_reduce<<<dim3(512), dim3(256), 0, stream>>>(parts, p_ws, pb, out, 8);
  } else {
    k_reduce<<<dim3(512), dim3(256), 0, stream>>>(parts, p_ws, pb, out, 0);
    k_gemm<8, true><<<dim3(512), dim3(128), 0, stream>>>(xl, p_ws, pwb, out);
  }
}